// Round 1
// baseline (610.976 us; speedup 1.0000x reference)
//
#include <hip/hip_runtime.h>

// Problem constants (B,T,F fixed by setup_inputs)
#define BB 32
#define TT 4096
#define FF 1024
#define K_NOR 5
#define K_ABN 10
#define K_HARD 10
#define K_TOT (K_NOR + K_ABN + K_HARD)   // 25 selected rows per batch

// Flat output offsets (return order of the reference tuple)
#define OFF_FEAT_NOR   0
#define OFF_SCORE_NOR  (BB * K_NOR * FF)                    // 163840
#define OFF_IDX_NOR    (OFF_SCORE_NOR + BB * K_NOR)         // 164000
#define OFF_FEAT_ABN   (OFF_IDX_NOR + BB * K_NOR)           // 164160
#define OFF_SCORE_ABN  (OFF_FEAT_ABN + BB * K_ABN * FF)     // 491840
#define OFF_FEAT_HARD  (OFF_SCORE_ABN + BB * K_ABN)         // 492160
#define OFF_SCORE_HARD (OFF_FEAT_HARD + BB * K_HARD * FF)   // 819840
#define OFF_IDX_HARD   (OFF_SCORE_HARD + BB * K_HARD)       // 820160
// total = 820480

// Kernel 1: per-batch-row top-k selection. One block per row.
// Matches jax.lax.top_k: values descending, ties broken by lower index.
__global__ __launch_bounds__(256) void topk_kernel(
    const float* __restrict__ score,
    float* __restrict__ out,
    int* __restrict__ ws_idx) {
  __shared__ float s[TT];
  __shared__ float key[TT];
  __shared__ float rk[256];
  __shared__ int   ri[256];
  __shared__ int   sel[K_ABN];  // max K per phase

  const int b   = blockIdx.x;
  const int tid = threadIdx.x;
  const float* srow = score + (size_t)b * TT;

  for (int t = tid; t < TT; t += 256) s[t] = srow[t];
  __syncthreads();

  for (int phase = 0; phase < 3; ++phase) {
    const int K = (phase == 0) ? K_NOR : ((phase == 1) ? K_ABN : K_HARD);

    // Build selection key for this phase
    for (int t = tid; t < TT; t += 256) {
      float v = s[t];
      key[t] = (phase == 0) ? -v : ((phase == 1) ? v : -fabsf(v - 0.5f));
    }
    __syncthreads();

    for (int k = 0; k < K; ++k) {
      // Thread-local argmax over strided slice (ascending t -> ties keep lower idx)
      float bk = -INFINITY;
      int   bi = TT;
      for (int t = tid; t < TT; t += 256) {
        float kv = key[t];
        if (kv > bk) { bk = kv; bi = t; }
      }
      rk[tid] = bk;
      ri[tid] = bi;
      __syncthreads();
      // Tree reduction; tie -> lower index
      for (int stride = 128; stride > 0; stride >>= 1) {
        if (tid < stride) {
          float ok = rk[tid + stride];
          int   oi = ri[tid + stride];
          if (ok > rk[tid] || (ok == rk[tid] && oi < ri[tid])) {
            rk[tid] = ok;
            ri[tid] = oi;
          }
        }
        __syncthreads();
      }
      if (tid == 0) {
        int w = ri[0];
        sel[k] = w;
        key[w] = -INFINITY;  // mask out for next selection
      }
      __syncthreads();
    }

    // Emit scores / indices for this phase
    if (tid < K) {
      int   w  = sel[tid];
      float sv = s[w];
      if (phase == 0) {
        out[OFF_SCORE_NOR + b * K_NOR + tid] = sv;
        out[OFF_IDX_NOR   + b * K_NOR + tid] = (float)w;
        ws_idx[b * K_TOT + tid] = w;
      } else if (phase == 1) {
        out[OFF_SCORE_ABN + b * K_ABN + tid] = sv;
        ws_idx[b * K_TOT + K_NOR + tid] = w;
      } else {
        out[OFF_SCORE_HARD + b * K_HARD + tid] = sv;
        out[OFF_IDX_HARD   + b * K_HARD + tid] = (float)w;
        ws_idx[b * K_TOT + K_NOR + K_ABN + tid] = w;
      }
    }
    __syncthreads();
  }
}

// Kernel 2: gather selected feature rows. One block per (b, slot).
// 256 threads x float4 = 1024 floats = one feature row.
__global__ __launch_bounds__(256) void gather_kernel(
    const float* __restrict__ feat,
    const int* __restrict__ ws_idx,
    float* __restrict__ out) {
  const int r    = blockIdx.x;       // 0 .. BB*K_TOT-1
  const int b    = r / K_TOT;
  const int slot = r % K_TOT;
  const int idx  = ws_idx[r];

  size_t dst;
  if (slot < K_NOR) {
    dst = OFF_FEAT_NOR + ((size_t)b * K_NOR + slot) * FF;
  } else if (slot < K_NOR + K_ABN) {
    dst = OFF_FEAT_ABN + ((size_t)b * K_ABN + (slot - K_NOR)) * FF;
  } else {
    dst = OFF_FEAT_HARD + ((size_t)b * K_HARD + (slot - K_NOR - K_ABN)) * FF;
  }

  const float4* src = (const float4*)(feat + ((size_t)b * TT + idx) * FF);
  float4* d = (float4*)(out + dst);
  d[threadIdx.x] = src[threadIdx.x];
}

extern "C" void kernel_launch(void* const* d_in, const int* in_sizes, int n_in,
                              void* d_out, int out_size, void* d_ws, size_t ws_size,
                              hipStream_t stream) {
  const float* feat  = (const float*)d_in[0];   // [32, 4096, 1024] fp32
  const float* score = (const float*)d_in[1];   // [32, 4096] fp32
  float* out = (float*)d_out;
  int* ws_idx = (int*)d_ws;                     // [32][25] selected indices

  topk_kernel<<<BB, 256, 0, stream>>>(score, out, ws_idx);
  gather_kernel<<<BB * K_TOT, 256, 0, stream>>>(feat, ws_idx, out);
}

// Round 2
// 575.674 us; speedup vs baseline: 1.0613x; 1.0613x over previous
//
#include <hip/hip_runtime.h>

// Problem constants (B,T,F fixed by setup_inputs)
#define BB 32
#define TT 4096
#define FF 1024
#define K_NOR 5
#define K_ABN 10
#define K_HARD 10

// Flat output offsets (return order of the reference tuple)
#define OFF_FEAT_NOR   0
#define OFF_SCORE_NOR  (BB * K_NOR * FF)                    // 163840
#define OFF_IDX_NOR    (OFF_SCORE_NOR + BB * K_NOR)         // 164000
#define OFF_FEAT_ABN   (OFF_IDX_NOR + BB * K_NOR)           // 164160
#define OFF_SCORE_ABN  (OFF_FEAT_ABN + BB * K_ABN * FF)     // 491840
#define OFF_FEAT_HARD  (OFF_SCORE_ABN + BB * K_ABN)         // 492160
#define OFF_SCORE_HARD (OFF_FEAT_HARD + BB * K_HARD * FF)   // 819840
#define OFF_IDX_HARD   (OFF_SCORE_HARD + BB * K_HARD)       // 820160
// total = 820480

// Fused top-k + gather. Grid = (32 rows, 3 phases); one block per (row, phase).
// Selection: incremental argmax — each thread keeps a running local best over
// its 16-element slice; per pick: 6-step shfl_xor wave reduce (no barriers) +
// 4-entry cross-wave LDS combine (2 barriers); only the winner's owner thread
// rescans its 16 LDS elements. Ties -> lower index (jax.lax.top_k semantics).
// Then the same block gathers its K feature rows (256 threads x float4 = one
// 1024-float row per iteration).
__global__ __launch_bounds__(256) void topk_gather_kernel(
    const float* __restrict__ score,
    const float* __restrict__ feat,
    float* __restrict__ out) {
  __shared__ float sbuf[TT];     // raw scores
  __shared__ float key[TT];      // phase-specific selection key
  __shared__ float wk[4];
  __shared__ int   wi[4];
  __shared__ int   sel_arr[K_ABN];

  const int b     = blockIdx.x;
  const int phase = blockIdx.y;   // 0=conf_nor(K=5), 1=conf_abn(K=10), 2=hard(K=10)
  const int tid   = threadIdx.x;
  const int K     = (phase == 0) ? K_NOR : K_ABN;

  const float4* srow4 = (const float4*)(score + (size_t)b * TT);

  // Load row (coalesced float4), build keys, compute thread-local argmax.
  // Thread t owns quads {t, t+256, t+512, t+768} -> elements 4q..4q+3.
  // Owner of element e = (e>>2) & 255.
  float bk = -INFINITY;
  int   bi = TT;
  for (int q = tid; q < TT / 4; q += 256) {
    float4 v = srow4[q];
    float vv[4] = {v.x, v.y, v.z, v.w};
#pragma unroll
    for (int j = 0; j < 4; ++j) {
      int e = 4 * q + j;
      float val = vv[j];
      float kv = (phase == 0) ? -val : ((phase == 1) ? val : -fabsf(val - 0.5f));
      sbuf[e] = val;
      key[e]  = kv;
      if (kv > bk) { bk = kv; bi = e; }  // strict > keeps lowest index on ties
    }
  }
  // No barrier needed yet: key[] slices are owner-exclusive; sbuf[] is only
  // read after the selection loop's barriers.

  int my_sel = 0;  // thread tid==k records the k-th winner
  for (int k = 0; k < K; ++k) {
    // Wave-level butterfly reduction of (key, idx); lexicographic max on (k,-i).
    float rk = bk;
    int   ri = bi;
#pragma unroll
    for (int m = 1; m < 64; m <<= 1) {
      float ok = __shfl_xor(rk, m, 64);
      int   oi = __shfl_xor(ri, m, 64);
      if (ok > rk || (ok == rk && oi < ri)) { rk = ok; ri = oi; }
    }
    if ((tid & 63) == 0) { wk[tid >> 6] = rk; wi[tid >> 6] = ri; }
    __syncthreads();
    float gk = wk[0];
    int   gi = wi[0];
#pragma unroll
    for (int w = 1; w < 4; ++w) {
      float ok = wk[w]; int oi = wi[w];
      if (ok > gk || (ok == gk && oi < gi)) { gk = ok; gi = oi; }
    }
    __syncthreads();  // protect wk/wi reuse in next iteration

    if (tid == k) my_sel = gi;

    // Winner's owner removes it and rescans its private 16-element slice.
    if (((gi >> 2) & 255) == tid) {
      key[gi] = -INFINITY;
      bk = -INFINITY;
      bi = TT;
      for (int q = tid; q < TT / 4; q += 256) {
#pragma unroll
        for (int j = 0; j < 4; ++j) {
          int e = 4 * q + j;
          float kv = key[e];
          if (kv > bk) { bk = kv; bi = e; }
        }
      }
    }
  }

  // Broadcast selected indices to the whole block.
  if (tid < K) sel_arr[tid] = my_sel;
  __syncthreads();

  // Emit scores / indices.
  if (tid < K) {
    float sv = sbuf[my_sel];
    if (phase == 0) {
      out[OFF_SCORE_NOR + b * K_NOR + tid] = sv;
      out[OFF_IDX_NOR   + b * K_NOR + tid] = (float)my_sel;
    } else if (phase == 1) {
      out[OFF_SCORE_ABN + b * K_ABN + tid] = sv;
    } else {
      out[OFF_SCORE_HARD + b * K_HARD + tid] = sv;
      out[OFF_IDX_HARD   + b * K_HARD + tid] = (float)my_sel;
    }
  }

  // Gather K feature rows: 256 threads x float4 = 4 KB = one row per iter.
  size_t base = (phase == 0) ? (OFF_FEAT_NOR + (size_t)b * K_NOR * FF)
              : (phase == 1) ? (OFF_FEAT_ABN + (size_t)b * K_ABN * FF)
                             : (OFF_FEAT_HARD + (size_t)b * K_HARD * FF);
  for (int k = 0; k < K; ++k) {
    int idx = sel_arr[k];
    const float4* src = (const float4*)(feat + ((size_t)b * TT + idx) * FF);
    float4* dst = (float4*)(out + base + (size_t)k * FF);
    dst[tid] = src[tid];
  }
}

extern "C" void kernel_launch(void* const* d_in, const int* in_sizes, int n_in,
                              void* d_out, int out_size, void* d_ws, size_t ws_size,
                              hipStream_t stream) {
  const float* feat  = (const float*)d_in[0];   // [32, 4096, 1024] fp32
  const float* score = (const float*)d_in[1];   // [32, 4096] fp32
  float* out = (float*)d_out;

  topk_gather_kernel<<<dim3(BB, 3), 256, 0, stream>>>(score, feat, out);
}